// Round 7
// baseline (296.479 us; speedup 1.0000x reference)
//
#include <hip/hip_runtime.h>
#include <hip/hip_bf16.h>

// Problem constants (B,S,H,E) = (64,1024,256,256)
#define S_LEN 1024
#define B_DIM 64
#define H_DIM 256
#define E_DIM 256
#define M_ROWS (B_DIM * S_LEN)   // 65536 rows

#define CT_COLS 32                 // output cols per block
#define NCT (E_DIM / CT_COLS)      // 8 col-tiles
#define CHUNK_R 256                // rows per chunk
#define NCHUNKS (S_LEN / CHUNK_R)  // 4
#define NTHREADS 1024
#define NWAVES 16

typedef __attribute__((ext_vector_type(8))) short bf16x8;
typedef __attribute__((ext_vector_type(4))) float f32x4;

__device__ __forceinline__ short cvt1(float f) {
  union { float ff; unsigned u; } t;
  t.ff = f;
  unsigned u = t.u;
  return (short)((u + 0x7fffu + ((u >> 16) & 1u)) >> 16);  // RNE
}

__device__ __forceinline__ bf16x8 cvt8v(float4 x, float4 y) {
  bf16x8 r;
  r[0] = cvt1(x.x); r[1] = cvt1(x.y); r[2] = cvt1(x.z); r[3] = cvt1(x.w);
  r[4] = cvt1(y.x); r[5] = cvt1(y.y); r[6] = cvt1(y.z); r[7] = cvt1(y.w);
  return r;
}

// fast tanh: 1 - 2/(e^{2x}+1)
__device__ __forceinline__ float fast_tanh(float x) {
  float t = __expf(2.0f * x);
  return 1.0f - 2.0f * __builtin_amdgcn_rcpf(t + 1.0f);
}

// Kernel 1: w[b,s] = exp(dot(alpha[b,s,:], Wa) + ba) * mask[b,s]
__global__ __launch_bounds__(256) void w_kernel(
    const float* __restrict__ alpha, const float* __restrict__ Wa,
    const float* __restrict__ ba, const float* __restrict__ mask,
    float* __restrict__ wv) {
  int wave = threadIdx.x >> 6, lane = threadIdx.x & 63;
  long long row = (long long)blockIdx.x * 4 + wave;
  const float4 a = reinterpret_cast<const float4*>(alpha + row * H_DIM)[lane];
  const float4 wa = reinterpret_cast<const float4*>(Wa)[lane];
  float d = a.x * wa.x + a.y * wa.y + a.z * wa.z + a.w * wa.w;
#pragma unroll
  for (int m = 32; m; m >>= 1) d += __shfl_xor(d, m);
  if (lane == 0) wv[row] = expf(d + ba[0]) * mask[row];
}

// Kernel 2: invacc[b,i] = 1 / (suffix_sum_{j>=i} w[b,j] + 1e-10)
__global__ __launch_bounds__(1024) void acc_kernel(
    const float* __restrict__ wv, float* __restrict__ invacc) {
  __shared__ float s[2][S_LEN];
  int b = blockIdx.x, i = threadIdx.x;
  s[0][i] = wv[b * S_LEN + i];
  __syncthreads();
  int src = 0;
#pragma unroll
  for (int off = 1; off < S_LEN; off <<= 1) {
    float v = s[src][i];
    if (i + off < S_LEN) v += s[src][i + off];
    s[src ^ 1][i] = v;
    __syncthreads();
    src ^= 1;
  }
  invacc[b * S_LEN + i] = 1.0f / (s[src][i] + 1e-10f);
}

// Kernel 3 (fused): block = (batch b, 32-col tile). Grid 512 -> 2 blocks/CU,
// 32 waves/CU (launch_bounds(1024,8) caps VGPR at 64). XCD-remapped so all
// 8 col-tiles of a batch share one XCD's L2. Bsm is XOR-swizzled on 16B
// granules (T2) -> conflict-free ds_read_b128. In-register suffix scan,
// one barrier per chunk via double-buffered segsum/carry.
__global__ __launch_bounds__(NTHREADS, 8) void fused_kernel(
    const float* __restrict__ beta, const float* __restrict__ Wb,
    const float* __restrict__ bb, const float* __restrict__ embed,
    const float* __restrict__ wv, const float* __restrict__ invacc,
    float* __restrict__ out) {
  __shared__ short Bsm[CT_COLS * H_DIM];           // 16 KB bf16 Wb col-tile
  __shared__ float segsum[2][NWAVES * CT_COLS];    // 4 KB (double-buffered)
  __shared__ float carry[2][CT_COLS];              // cross-chunk carry

  const int tid = threadIdx.x;
  // XCD remap: all 8 ct of batch b -> same XCD (hw mod 8 fixed per b).
  const int hw = blockIdx.x;
  const int b = ((hw & 7) << 3) | ((hw >> 3) & 7);
  const int colbase = (hw >> 6) * CT_COLS;

  // ---- stage Wb col-tile -> bf16 LDS, XOR-swizzled 16B granules
  {
    int row = tid >> 5;          // 0..31 = col c within tile
    int g = tid & 31;            // granule (8 bf16 = 16B) within row
    const float4* src =
        reinterpret_cast<const float4*>(Wb + (long long)(colbase + row) * H_DIM + g * 8);
    float4 v0 = src[0], v1 = src[1];
    int gs = g ^ (row & 7);
    *reinterpret_cast<bf16x8*>(&Bsm[row * H_DIM + gs * 8]) = cvt8v(v0, v1);
  }
  if (tid < CT_COLS) { carry[0][tid] = 0.f; carry[1][tid] = 0.f; }
  __syncthreads();

  const int wave = tid >> 6, lane = tid & 63;
  const int rl = lane & 15, kg = lane >> 4;
  const int sw = rl & 7;         // row-XOR for swizzled reads

  // bb hoisted
  float bbv[2];
#pragma unroll
  for (int j = 0; j < 2; ++j) bbv[j] = bb[colbase + j * 16 + rl];

  // A-pipeline (depth 2, rolls across chunks)
  const float* ap =
      beta + ((long long)b * S_LEN + 3 * CHUNK_R + wave * 16 + rl) * H_DIM + kg * 8;
  float4 pa0 = *reinterpret_cast<const float4*>(ap + 0);
  float4 pa1 = *reinterpret_cast<const float4*>(ap + 4);
  float4 pb0 = *reinterpret_cast<const float4*>(ap + 32);
  float4 pb1 = *reinterpret_cast<const float4*>(ap + 36);

  for (int chunk = NCHUNKS - 1; chunk >= 0; --chunk) {
    const int nc = (chunk > 0) ? chunk - 1 : 0;
    const long long r0 = (long long)b * S_LEN + chunk * CHUNK_R + wave * 16;
    const float* ap_next =
        beta + ((long long)b * S_LEN + nc * CHUNK_R + wave * 16 + rl) * H_DIM + kg * 8;

    f32x4 acc[2] = {{0.f,0.f,0.f,0.f},{0.f,0.f,0.f,0.f}};

#pragma unroll
    for (int ks = 0; ks < 8; ++ks) {
      float4 n0, n1;
      if (ks < 6) {
        n0 = *reinterpret_cast<const float4*>(ap + (ks + 2) * 32);
        n1 = *reinterpret_cast<const float4*>(ap + (ks + 2) * 32 + 4);
      } else {  // roll into next chunk's first two k-tiles
        n0 = *reinterpret_cast<const float4*>(ap_next + (ks - 6) * 32);
        n1 = *reinterpret_cast<const float4*>(ap_next + (ks - 6) * 32 + 4);
      }
      bf16x8 am = cvt8v(pa0, pa1);
      int g0 = (ks * 4 + kg);
#pragma unroll
      for (int j = 0; j < 2; ++j) {
        bf16x8 bn = *reinterpret_cast<const bf16x8*>(
            &Bsm[(j * 16 + rl) * H_DIM + (g0 ^ sw) * 8]);
        acc[j] = __builtin_amdgcn_mfma_f32_16x16x32_bf16(am, bn, acc[j], 0, 0, 0);
      }
      pa0 = pb0; pa1 = pb1; pb0 = n0; pb1 = n1;
    }
    ap = ap_next;

    // ---- epilogue + in-register suffix scan
    // D frag: col = j*16 + rl, row-in-16 = kg*4 + q  [m89/m91]
    const int rd = chunk & 1;
    const long long rq = r0 + kg * 4;
    float wvq[4], inv[4];
#pragma unroll
    for (int q = 0; q < 4; ++q) {
      wvq[q] = wv[rq + q];
      inv[q] = invacc[rq + q];
    }

    float sv[2][4], off[2];
#pragma unroll
    for (int j = 0; j < 2; ++j) {
      int c = j * 16 + rl;
      int e = colbase + c;
      float p[4];
#pragma unroll
      for (int q = 0; q < 4; ++q)
        p[q] = wvq[q] * fast_tanh(acc[j][q] + bbv[j]) * embed[(rq + q) * E_DIM + e];
      sv[j][3] = p[3];
      sv[j][2] = p[2] + sv[j][3];
      sv[j][1] = p[1] + sv[j][2];
      sv[j][0] = p[0] + sv[j][1];
      float gtot = sv[j][0];
      float t16 = __shfl_xor(gtot, 16);
      float t32 = __shfl_xor(gtot, 32);
      float t48 = __shfl_xor(gtot, 48);
      off[j] = (kg == 0) ? (t16 + t32 + t48)
             : (kg == 1) ? (t32 + t48)
             : (kg == 2) ? t16 : 0.f;
      float wtot = gtot + t16 + t32 + t48;
      if (kg == 0) segsum[rd][wave * CT_COLS + c] = wtot;
    }
    __syncthreads();  // segsum[rd] visible; carry[rd] stable

#pragma unroll
    for (int j = 0; j < 2; ++j) {
      int c = j * 16 + rl;
      float segoff = carry[rd][c];
#pragma unroll
      for (int w2 = 0; w2 < NWAVES; ++w2) {
        float t = segsum[rd][w2 * CT_COLS + c];
        segoff += (w2 > wave) ? t : 0.f;
      }
      off[j] += segoff;
      if (wave == 0 && kg == 0) carry[rd ^ 1][c] = off[j] + sv[j][0];
#pragma unroll
      for (int q = 0; q < 4; ++q)
        out[(rq + q) * E_DIM + colbase + c] = (sv[j][q] + off[j]) * inv[q];
    }
    // no trailing barrier: next chunk uses the other segsum/carry buffer
  }
}

extern "C" void kernel_launch(void* const* d_in, const int* in_sizes, int n_in,
                              void* d_out, int out_size, void* d_ws,
                              size_t ws_size, hipStream_t stream) {
  const float* alpha = (const float*)d_in[0];  // [B,S,H]
  const float* beta = (const float*)d_in[1];   // [B,S,H]
  const float* embed = (const float*)d_in[2];  // [B,S,E]
  const float* mask = (const float*)d_in[3];   // [B,S]
  const float* Wb = (const float*)d_in[4];     // [E,H]
  const float* bb = (const float*)d_in[5];     // [E]
  const float* Wa = (const float*)d_in[6];     // [H]
  const float* ba = (const float*)d_in[7];     // [1]
  float* out = (float*)d_out;                  // [B,S,E]

  // Workspace: wv[65536] | invacc[65536]
  float* wv = (float*)d_ws;
  float* invacc = wv + M_ROWS;

  w_kernel<<<M_ROWS / 4, 256, 0, stream>>>(alpha, Wa, ba, mask, wv);
  acc_kernel<<<B_DIM, 1024, 0, stream>>>(wv, invacc);
  fused_kernel<<<B_DIM * NCT, NTHREADS, 0, stream>>>(beta, Wb, bb, embed, wv,
                                                     invacc, out);
}